// Round 15
// baseline (439.493 us; speedup 1.0000x reference)
//
#include <hip/hip_runtime.h>
#include <hip/hip_bf16.h>

typedef __bf16 bf16x8 __attribute__((ext_vector_type(8)));
typedef unsigned short u16x8 __attribute__((ext_vector_type(8)));
typedef float f32x4 __attribute__((ext_vector_type(4)));

#define NTOK 49
#define NH   6
#define HDIM 56
#define DIMC 192
#define SCALE 0.17677669529663687f

// ---------------- workspace layout (bytes) ----------------
#define WS_QKVWT   0u          // bf16 [1008][192] transposed qkv_w, q-cols pre-scaled
#define WS_PROJWT  387072u     // bf16 [192][352]  transposed proj_w, K padded 336->352 w/ zeros
#define WS_QKVBS   522240u     // f32  [1008]      qkv_b, q-entries pre-scaled
#define WS_BMALLT  526272u     // bf16 [64][6][64 n][64 m] transposed bias+mask (linear)
#define WS_LEPET   3672000u    // f32  [9][336]    lepe_w transposed (tap-major)
#define WS_QKV     3684288u    // bf16 [100352][1008] qkv activations (q-slot later holds O+lepe)
#define WS_NEED    (WS_QKV + (size_t)100352 * 2016 + 4096)
// tier-1 extras: bf16 copy of x
#define WS_XBF     (WS_QKV + (size_t)100352 * 2016)            // bf16 [100352][192]
#define WS_NEED2   (WS_XBF + (size_t)100352 * 384 + 4096)      // ~245 MB
// fallback path (R2 layout, 591KB):
#define FB_QKVWT  0
#define FB_PROJWT 387072
#define FB_BIAS6  534528

// Full-address XOR swizzle. Safe (globally bijective) for strides that are
// multiples of 128, or ≡64 mod 128.
__device__ __forceinline__ unsigned swzaddr(unsigned base, int row, int colb, int strideb) {
  return base + (unsigned)((row * strideb + colb) ^ ((row & 7) << 4));
}

__device__ __forceinline__ unsigned short f2bu(float f) {
  __hip_bfloat16 h = __float2bfloat16(f);
  unsigned short u;
  __builtin_memcpy(&u, &h, 2);
  return u;
}

__device__ __forceinline__ float bu2f(unsigned short u) {
  union { unsigned int i; float f; } x;
  x.i = ((unsigned int)u) << 16;
  return x.f;
}

// ==================== MAIN PATH ====================

// prep body (idx-parameterized so it can be fused with xcvt)
__device__ __forceinline__ void prep_body(
    int idx,
    const float* __restrict__ qkv_w, const float* __restrict__ qkv_b,
    const float* __restrict__ proj_w, const float* __restrict__ tbl,
    const int* __restrict__ ridx, const float* __restrict__ mask,
    const float* __restrict__ lepe_w, unsigned char* __restrict__ ws) {
  __hip_bfloat16* qkvwt   = (__hip_bfloat16*)(ws + WS_QKVWT);
  __hip_bfloat16* projwt2 = (__hip_bfloat16*)(ws + WS_PROJWT);
  float*          qkvbs   = (float*)(ws + WS_QKVBS);
  __hip_bfloat16* bmallT  = (__hip_bfloat16*)(ws + WS_BMALLT);
  float*          lepeT   = (float*)(ws + WS_LEPET);
  const int n1 = 1008 * 192;        // qkvwt
  const int n2 = 192 * 352;         // projwt2
  const int n3 = 1008;              // qkvbs
  const int n4 = 64 * 6 * 64 * 64;  // bmallT
  const int n5 = 9 * 336;           // lepeT
  if (idx < n1) {
    int c = idx / 192, k = idx - c * 192;
    float v = qkv_w[k * 1008 + c];
    if (c % 168 < 56) v *= SCALE;
    qkvwt[idx] = __float2bfloat16(v);
  } else if (idx < n1 + n2) {
    int j = idx - n1;
    int n = j / 352, kk = j - n * 352;
    projwt2[j] = __float2bfloat16(kk < 336 ? proj_w[kk * 192 + n] : 0.0f);
  } else if (idx < n1 + n2 + n3) {
    int c = idx - n1 - n2;
    float v = qkv_b[c];
    if (c % 168 < 56) v *= SCALE;
    qkvbs[c] = v;
  } else if (idx < n1 + n2 + n3 + n4) {
    int j = idx - n1 - n2 - n3;
    int wh = j >> 12;
    int e = j & 4095;
    int n = e >> 6, m = e & 63;
    int wdx = wh / 6, h = wh - wdx * 6;
    float v;
    if (n >= NTOK) v = -1e30f;
    else if (m >= NTOK) v = 0.0f;
    else v = tbl[ridx[m * NTOK + n] * NH + h] + mask[wdx * (NTOK * NTOK) + m * NTOK + n];
    bmallT[j] = __float2bfloat16(v);
  } else if (idx < n1 + n2 + n3 + n4 + n5) {
    int j = idx - n1 - n2 - n3 - n4;
    int tap = j / 336, hd = j - tap * 336;
    lepeT[j] = lepe_w[hd * 9 + tap];
  }
}

// fused prep + xcvt: blocks [0,9408) convert x->bf16; the rest run prep.
#define XCVT_BLOCKS 9408
__global__ __launch_bounds__(256) void prep_all(
    const float* __restrict__ x,
    const float* __restrict__ qkv_w, const float* __restrict__ qkv_b,
    const float* __restrict__ proj_w, const float* __restrict__ tbl,
    const int* __restrict__ ridx, const float* __restrict__ mask,
    const float* __restrict__ lepe_w, unsigned char* __restrict__ ws) {
  int bid = blockIdx.x;
  if (bid < XCVT_BLOCKS) {
    unsigned char* xbf = ws + WS_XBF;
    int i = bid * 256 + threadIdx.x;
    if (i >= 2408448) return;
    const float4* p = (const float4*)(x + (size_t)i * 8);
    float4 a = p[0], b = p[1];
    union { unsigned short u[8]; uint4 q; } pk;
    pk.u[0] = f2bu(a.x); pk.u[1] = f2bu(a.y); pk.u[2] = f2bu(a.z); pk.u[3] = f2bu(a.w);
    pk.u[4] = f2bu(b.x); pk.u[5] = f2bu(b.y); pk.u[6] = f2bu(b.z); pk.u[7] = f2bu(b.w);
    *(uint4*)(xbf + (size_t)i * 16) = pk.q;
  } else {
    int idx = (bid - XCVT_BLOCKS) * 256 + threadIdx.x;
    prep_body(idx, qkv_w, qkv_b, proj_w, tbl, ridx, mask, lepe_w, ws);
  }
}

// tier-2 prep (no xcvt)
__global__ void prep_main(const float* __restrict__ qkv_w,
                          const float* __restrict__ qkv_b,
                          const float* __restrict__ proj_w,
                          const float* __restrict__ tbl,
                          const int* __restrict__ ridx,
                          const float* __restrict__ mask,
                          const float* __restrict__ lepe_w,
                          unsigned char* __restrict__ ws) {
  prep_body(blockIdx.x * 256 + threadIdx.x, qkv_w, qkv_b, proj_w, tbl, ridx, mask,
            lepe_w, ws);
}

// K1 (tier-1): qkv = xbf @ Wqkv + b. BM=64, BN=144, K in 3 thirds of 64 cols
// ([144][64el] @128B stride, 18432B; LDS alloc 20480B). Software-pipelined:
// B-chunks + A-frags of third t+1 are prefetched into REGISTERS before the
// MFMAs of third t (load latency hides under 18 MFMAs); the ds_write of t+1
// happens after the post-MFMA barrier (all waves done reading t). Epilogue is
// per-wave (own 16 rows; same-wave in-order DS) after one barrier.
__global__ __launch_bounds__(256, 2) void qkv_gemm5(unsigned char* __restrict__ ws) {
  __shared__ uint4 smem4[1280];   // 20480 B
  unsigned char* sm = (unsigned char*)smem4;
  const unsigned char* qkvwtb = ws + WS_QKVWT;
  const float* qkvbs = (const float*)(ws + WS_QKVBS);
  const unsigned char* xbf = ws + WS_XBF;
  unsigned char* qkvbuf = ws + WS_QKV;

  const int tid = threadIdx.x;
  const int lane = tid & 63, wv = tid >> 6;
  const int l15 = lane & 15, l4 = lane >> 4;
  const int b = blockIdx.x;
  const int j = (b & 7) * 1372 + (b >> 3);   // 10976 = 8*1372
  const int nbase = (j % 7) * 144;
  const int mbase = (j / 7) * 64;

  f32x4 acc[9];
#pragma unroll
  for (int nt = 0; nt < 9; ++nt) {
    float bb = qkvbs[nbase + nt * 16 + l15];
    acc[nt] = (f32x4){bb, bb, bb, bb};
  }
  const unsigned char* xrow = xbf + (size_t)(mbase + wv * 16 + l15) * 384;

  uint4 sreg[5];
  bf16x8 a0, a1, na0, na1;

  // prologue: load third 0 (B chunks -> regs, A frags), write to LDS, sync
#pragma unroll
  for (int i = 0; i < 5; ++i) {
    int jj = tid + 256 * i;
    if (jj < 1152) {
      int row = jj >> 3, c16 = jj & 7;
      sreg[i] = *(const uint4*)(qkvwtb + (size_t)(nbase + row) * 384 + c16 * 16);
    }
  }
  a0 = *(const bf16x8*)(xrow + l4 * 16);
  a1 = *(const bf16x8*)(xrow + 64 + l4 * 16);
#pragma unroll
  for (int i = 0; i < 5; ++i) {
    int jj = tid + 256 * i;
    if (jj < 1152) {
      int row = jj >> 3, c16 = jj & 7;
      *(uint4*)(sm + swzaddr(0, row, c16 * 16, 128)) = sreg[i];
    }
  }
  __syncthreads();

#pragma unroll
  for (int t = 0; t < 3; ++t) {
    // prefetch third t+1 into registers (overlaps with MFMAs below)
    if (t < 2) {
#pragma unroll
      for (int i = 0; i < 5; ++i) {
        int jj = tid + 256 * i;
        if (jj < 1152) {
          int row = jj >> 3, c16 = jj & 7;
          sreg[i] = *(const uint4*)(qkvwtb + (size_t)(nbase + row) * 384 +
                                    (t + 1) * 128 + c16 * 16);
        }
      }
      na0 = *(const bf16x8*)(xrow + (t + 1) * 128 + l4 * 16);
      na1 = *(const bf16x8*)(xrow + (t + 1) * 128 + 64 + l4 * 16);
    }
    // MFMAs on third t
#pragma unroll
    for (int kt2 = 0; kt2 < 2; ++kt2) {
      bf16x8 a = kt2 ? a1 : a0;
#pragma unroll
      for (int nt = 0; nt < 9; ++nt) {
        bf16x8 bf = *(const bf16x8*)(sm + swzaddr(0, nt * 16 + l15, kt2 * 64 + l4 * 16, 128));
        acc[nt] = __builtin_amdgcn_mfma_f32_16x16x32_bf16(a, bf, acc[nt], 0, 0, 0);
      }
    }
    __syncthreads();               // all waves done reading third t
    if (t < 2) {
#pragma unroll
      for (int i = 0; i < 5; ++i) {
        int jj = tid + 256 * i;
        if (jj < 1152) {
          int row = jj >> 3, c16 = jj & 7;
          *(uint4*)(sm + swzaddr(0, row, c16 * 16, 128)) = sreg[i];
        }
      }
      a0 = na0; a1 = na1;
      __syncthreads();             // third t+1 visible to all waves
    }
  }

  // epilogue: per-wave C dump + copy-out (own 16 rows; no further barriers).
  // (the barrier after the last MFMA above makes the B-stage region dead)
#pragma unroll
  for (int nt = 0; nt < 9; ++nt)
#pragma unroll
    for (int r = 0; r < 4; ++r) {
      int row = wv * 16 + l4 * 4 + r;
      *(unsigned short*)(sm + swzaddr(0, row, (nt * 16 + l15) * 2, 320)) = f2bu(acc[nt][r]);
    }
#pragma unroll
  for (int i = 0; i < 5; ++i) {
    int jj = lane + 64 * i;        // 288 chunks per wave (16 rows x 18)
    if (jj < 288) {
      int row = wv * 16 + jj / 18, c16 = jj - (jj / 18) * 18;
      uint4 v = *(const uint4*)(sm + swzaddr(0, row, c16 * 16, 320));
      *(uint4*)(qkvbuf + (size_t)(mbase + row) * 2016 + nbase * 2 + c16 * 16) = v;
    }
  }
}

// K1 (tier-2): qkv from fp32 x with in-kernel cvt. BM=128.
__global__ __launch_bounds__(256, 2) void qkv_gemm(
    const float* __restrict__ x, unsigned char* __restrict__ ws) {
  __shared__ uint4 smem4[2560];   // 40960 B
  unsigned char* sm = (unsigned char*)smem4;
  const __hip_bfloat16* qkvwt = (const __hip_bfloat16*)(ws + WS_QKVWT);
  const float* qkvbs = (const float*)(ws + WS_QKVBS);
  unsigned char* qkvbuf = ws + WS_QKV;

  const int tid = threadIdx.x;
  const int lane = tid & 63, wv = tid >> 6;
  const int l15 = lane & 15, l4 = lane >> 4;
  const int b = blockIdx.x;
  const int j = (b & 7) * 686 + (b >> 3);     // 5488 = 8*686
  const int nbase = (j % 7) * 144;
  const int mbase = (j / 7) * 128;

  bf16x8 afr[2][6];
#pragma unroll
  for (int mt = 0; mt < 2; ++mt) {
    int g = mbase + wv * 32 + mt * 16 + l15;
    const float* xr = x + (size_t)g * DIMC;
#pragma unroll
    for (int kt = 0; kt < 6; ++kt) {
      const float4* p = (const float4*)(xr + kt * 32 + l4 * 8);
      float4 a = p[0], bb = p[1];
      union { unsigned short u[8]; bf16x8 v; } pk;
      pk.u[0] = f2bu(a.x); pk.u[1] = f2bu(a.y); pk.u[2] = f2bu(a.z); pk.u[3] = f2bu(a.w);
      pk.u[4] = f2bu(bb.x); pk.u[5] = f2bu(bb.y); pk.u[6] = f2bu(bb.z); pk.u[7] = f2bu(bb.w);
      afr[mt][kt] = pk.v;
    }
  }

  f32x4 acc[2][9];
#pragma unroll
  for (int nt = 0; nt < 9; ++nt) {
    float bb = qkvbs[nbase + nt * 16 + l15];
    acc[0][nt] = (f32x4){bb, bb, bb, bb};
    acc[1][nt] = (f32x4){bb, bb, bb, bb};
  }

#pragma unroll
  for (int kh = 0; kh < 2; ++kh) {
    if (kh) __syncthreads();
    for (int jj = tid; jj < 1728; jj += 256) {
      int row = jj / 12, c16 = jj - row * 12;
      uint4 v = *(const uint4*)((const unsigned char*)qkvwt +
                                (size_t)(nbase + row) * 384 + kh * 192 + c16 * 16);
      *(uint4*)(sm + swzaddr(0, row, c16 * 16, 256)) = v;
    }
    __syncthreads();
#pragma unroll
    for (int kt2 = 0; kt2 < 3; ++kt2) {
      const int kt = kh * 3 + kt2;
#pragma unroll
      for (int nt = 0; nt < 9; ++nt) {
        bf16x8 bf = *(const bf16x8*)(sm + swzaddr(0, nt * 16 + l15, kt2 * 64 + l4 * 16, 256));
        acc[0][nt] = __builtin_amdgcn_mfma_f32_16x16x32_bf16(afr[0][kt], bf, acc[0][nt], 0, 0, 0);
        acc[1][nt] = __builtin_amdgcn_mfma_f32_16x16x32_bf16(afr[1][kt], bf, acc[1][nt], 0, 0, 0);
      }
    }
  }
  __syncthreads();

#pragma unroll
  for (int mt = 0; mt < 2; ++mt)
#pragma unroll
    for (int nt = 0; nt < 9; ++nt)
#pragma unroll
      for (int r = 0; r < 4; ++r) {
        int row = wv * 32 + mt * 16 + l4 * 4 + r;
        *(unsigned short*)(sm + swzaddr(0, row, (nt * 16 + l15) * 2, 320)) =
            f2bu(acc[mt][nt][r]);
      }
  __syncthreads();
  for (int jj = tid; jj < 2304; jj += 256) {
    int row = jj / 18, c16 = jj - row * 18;
    uint4 v = *(const uint4*)(sm + swzaddr(0, row, c16 * 16, 320));
    *(uint4*)(qkvbuf + (size_t)(mbase + row) * 2016 + nbase * 2 + c16 * 16) = v;
  }
}

// K2 (R11-best variant, 123us measured): one block per (head, window),
// XCD-swizzled. LDS 32K: KS 8K (k, then P after barrier; O-dump overlays
// KS+VT) | VT 8K | VS 16K (v as f32 [64][64]@256B). bias+mask read direct
// from global (L2-hot).
#define A_KS   0u
#define A_VT   8192u
#define A_VS   16384u
#define A_SMEM 32768u

__global__ __launch_bounds__(256, 4) void attn_head(
    const float* __restrict__ lepe_b, unsigned char* __restrict__ ws) {
  __shared__ uint4 smem4[A_SMEM / 16];
  unsigned char* sm = (unsigned char*)smem4;
  const unsigned char* bmallT = ws + WS_BMALLT;
  const float* lepeT = (const float*)(ws + WS_LEPET);
  unsigned char* qkvbuf = ws + WS_QKV;

  const int tid = threadIdx.x;
  const int lane = tid & 63, wv = tid >> 6;
  const int l15 = lane & 15, l4 = lane >> 4;
  const int b = blockIdx.x;
  const int j = (b & 7) * 1536 + (b >> 3);    // 12288 = 8*1536
  const int h = j % 6;
  const int win = j / 6;
  const int wdx = win & 63;
  unsigned char* qbase = qkvbuf + (size_t)win * (NTOK * 2016);

  const int arow = wv * 16 + l15;
  const int xr = arow < NTOK ? arow : NTOK - 1;
  const int mc0 = wv * 16 + l4 * 4;

  // early independent global loads: q fragments + bias/mask rows (L2-hot 3MB table)
  bf16x8 qa[2];
#pragma unroll
  for (int kt = 0; kt < 2; ++kt)
    qa[kt] = *(const bf16x8*)(qbase + (size_t)xr * 2016 + h * 336 + kt * 64 + l4 * 16);
  unsigned long long bm8[4];
  {
    const unsigned char* bmrow = bmallT + (size_t)(wdx * NH + h) * 8192;
#pragma unroll
    for (int nt = 0; nt < 4; ++nt)
      bm8[nt] = *(const unsigned long long*)(bmrow + (nt * 16 + l15) * 128 + mc0 * 2);
  }

  // zero KS+VT (16KB): pads feed MFMA B-operands, must be exact 0.
  {
    uint4 z = {0u, 0u, 0u, 0u};
    for (int i = tid; i < 1024; i += 256) smem4[i] = z;
  }
  __syncthreads();

  // stage k (KS swizzled), v transposed (VT), v as f32 (VS); m-major lane map
  for (int jj = tid; jj < 343; jj += 256) {
    int m = jj % 49, c = jj / 49;
    const unsigned char* row = qbase + (size_t)m * 2016 + h * 336;
    uint4 kv = *(const uint4*)(row + 112 + c * 16);
    *(uint4*)(sm + swzaddr(A_KS, m, c * 16, 128)) = kv;
    uint4 vv = *(const uint4*)(row + 224 + c * 16);
    union { uint4 q; unsigned short u[8]; } pk; pk.q = vv;
#pragma unroll
    for (int e = 0; e < 8; ++e)
      *(unsigned short*)(sm + swzaddr(A_VT, c * 8 + e, m * 2, 128)) = pk.u[e];
    float4 vf0, vf1;
    vf0.x = bu2f(pk.u[0]); vf0.y = bu2f(pk.u[1]); vf0.z = bu2f(pk.u[2]); vf0.w = bu2f(pk.u[3]);
    vf1.x = bu2f(pk.u[4]); vf1.y = bu2f(pk.u[5]); vf1.z = bu2f(pk.u[6]); vf1.w = bu2f(pk.u[7]);
    *(float4*)(sm + swzaddr(A_VS, m, c * 32, 256)) = vf0;
    *(float4*)(sm + swzaddr(A_VS, m, c * 32 + 16, 256)) = vf1;
  }
  __syncthreads();

  // ---- S = (bias+mask) + q k^T ----
  f32x4 sv[4];
#pragma unroll
  for (int nt = 0; nt < 4; ++nt) {
#pragma unroll
    for (int r = 0; r < 4; ++r)
      sv[nt][r] = bu2f((unsigned short)(bm8[nt] >> (16 * r)));
    int n = nt * 16 + l15;
#pragma unroll
    for (int kt = 0; kt < 2; ++kt) {
      bf16x8 kb = *(const bf16x8*)(sm + swzaddr(A_KS, n, kt * 64 + l4 * 16, 128));
      sv[nt] = __builtin_amdgcn_mfma_f32_16x16x32_bf16(qa[kt], kb, sv[nt], 0, 0, 0);
    }
  }

  // ---- softmax over rows ----
#pragma unroll
  for (int r = 0; r < 4; ++r) {
    float mx = fmaxf(fmaxf(sv[0][r], sv[1][r]), fmaxf(sv[2][r], sv[3][r]));
    mx = fmaxf(mx, __shfl_xor(mx, 1));
    mx = fmaxf(mx, __shfl_xor(mx, 2));
    mx = fmaxf(mx, __shfl_xor(mx, 4));
    mx = fmaxf(mx, __shfl_xor(mx, 8));
    float p0 = __expf(sv[0][r] - mx), p1 = __expf(sv[1][r] - mx);
    float p2 = __expf(sv[2][r] - mx), p3 = __expf(sv[3][r] - mx);
    float sum = p0 + p1 + p2 + p3;
    sum += __shfl_xor(sum, 1);
    sum += __shfl_xor(sum, 2);
    sum += __shfl_xor(sum, 4);
    sum += __shfl_xor(sum, 8);
    float rinv = __builtin_amdgcn_rcpf(sum);
    sv[0][r] = p0 * rinv; sv[1][r] = p1 * rinv; sv[2][r] = p2 * rinv; sv[3][r] = p3 * rinv;
  }

  // all waves done reading KS -> safe to overwrite with P
  __syncthreads();
#pragma unroll
  for (int nt = 0; nt < 4; ++nt) {
    int n = nt * 16 + l15;
#pragma unroll
    for (int r = 0; r < 4; ++r) {
      int m = mc0 + r;
      if (m < NTOK)
        *(__hip_bfloat16*)(sm + swzaddr(A_KS, m, n * 2, 128)) = __float2bfloat16(sv[nt][r]);
    }
  }
  // pad rows 49..63 of KS still hold 0 from the initial zeroing; pad cols n>=49
  // hold exp(-1e30)=0 written above -> P pads exact 0.

  // ---- O = P @ V ----
  bf16x8 pa[2];
#pragma unroll
  for (int kt = 0; kt < 2; ++kt)
    pa[kt] = *(const bf16x8*)(sm + swzaddr(A_KS, arow, kt * 64 + l4 * 16, 128));
  f32x4 ov[4];
#pragma unroll
  for (int nt = 0; nt < 4; ++nt) {
    f32x4 a0 = (f32x4){0.f, 0.f, 0.f, 0.f};
#pragma unroll
    for (int kt = 0; kt < 2; ++kt) {
      bf16x8 vb = *(const bf16x8*)(sm + swzaddr(A_VT, nt * 16 + l15, kt * 64 + l4 * 16, 128));
      a0 = __builtin_amdgcn_mfma_f32_16x16x32_bf16(pa[kt], vb, a0, 0, 0, 0);
    }
    ov[nt] = a0;
  }

  // ---- dump O (f32) into KS+VT region (dead after PV) ----
  __syncthreads();
#pragma unroll
  for (int nt = 0; nt < 4; ++nt) {
    int d = nt * 16 + l15;
#pragma unroll
    for (int r = 0; r < 4; ++r) {
      int m = mc0 + r;
      *(float*)(sm + swzaddr(0, m, d * 4, 256)) = ov[nt][r];
    }
  }
  __syncthreads();

  // ---- fused: out[m][d0..d0+7] = O + lepe (VS f32, weights from L2) ----
  for (int jj = tid; jj < 343; jj += 256) {
    int m = jj % 49, c = jj / 49;
    int y = m / 7, x0 = m - y * 7;
    float4 a0 = *(const float4*)(sm + swzaddr(0, m, c * 32, 256));
    float4 a1 = *(const float4*)(sm + swzaddr(0, m, c * 32 + 16, 256));
    const float4* lb = (const float4*)(lepe_b + h * HDIM + c * 8);
    float4 b0 = lb[0], b1 = lb[1];
    a0.x += b0.x; a0.y += b0.y; a0.z += b0.z; a0.w += b0.w;
    a1.x += b1.x; a1.y += b1.y; a1.z += b1.z; a1.w += b1.w;
#pragma unroll
    for (int dy = 0; dy < 3; ++dy) {
      int yy = y + dy - 1;
      if (yy < 0 || yy >= 7) continue;
#pragma unroll
      for (int dx = 0; dx < 3; ++dx) {
        int xx = x0 + dx - 1;
        if (xx < 0 || xx >= 7) continue;
        int mp = yy * 7 + xx;
        float4 v0 = *(const float4*)(sm + swzaddr(A_VS, mp, c * 32, 256));
        float4 v1 = *(const float4*)(sm + swzaddr(A_VS, mp, c * 32 + 16, 256));
        const float4* wr = (const float4*)(lepeT + (dy * 3 + dx) * 336 + h * HDIM + c * 8);
        float4 w0 = wr[0], w1 = wr[1];
        a0.x += w0.x * v0.x; a0.y += w0.y * v0.y; a0.z += w0.z * v0.z; a0.w += w0.w * v0.w;
        a1.x += w1.x * v1.x; a1.y += w1.y * v1.y; a1.z += w1.z * v1.z; a1.w += w1.w * v1.w;
      }
    }
    union { unsigned short u[8]; uint4 q; } st;
    st.u[0] = f2bu(a0.x); st.u[1] = f2bu(a0.y); st.u[2] = f2bu(a0.z); st.u[3] = f2bu(a0.w);
    st.u[4] = f2bu(a1.x); st.u[5] = f2bu(a1.y); st.u[6] = f2bu(a1.z); st.u[7] = f2bu(a1.w);
    *(uint4*)(qbase + (size_t)m * 2016 + h * 336 + c * 16) = st.q;
  }
}

// K3: out = O @ projwt2 + b. XCD-swizzled.
__global__ __launch_bounds__(256, 3) void proj_gemm(
    const float* __restrict__ proj_b, unsigned char* __restrict__ ws,
    float* __restrict__ out) {
  __shared__ uint4 smem4[2816];   // 45056 B
  unsigned char* sm = (unsigned char*)smem4;
  const unsigned char* projwt2 = ws + WS_PROJWT;
  const unsigned char* qkvbuf = ws + WS_QKV;

  const int tid = threadIdx.x;
  const int lane = tid & 63, wv = tid >> 6;
  const int l15 = lane & 15, l4 = lane >> 4;
  const int b = blockIdx.x;
  const int j = (b & 7) * 294 + (b >> 3);     // 2352 = 8*294
  const int nbase = (j % 3) * 64;
  const int mbase = (j / 3) * 128;

  for (int jj = tid; jj < 2816; jj += 256) {
    int n = jj / 44, c = jj - n * 44;
    uint4 v = *(const uint4*)(projwt2 + (size_t)(nbase + n) * 704 + c * 16);
    *(uint4*)(sm + swzaddr(0, n, c * 16, 704)) = v;
  }
  f32x4 acc[2][4];
#pragma unroll
  for (int nt = 0; nt < 4; ++nt) {
    float bb = proj_b[nbase + nt * 16 + l15];
    acc[0][nt] = (f32x4){bb, bb, bb, bb};
    acc[1][nt] = (f32x4){bb, bb, bb, bb};
  }
  __syncthreads();

  for (int kt = 0; kt < 11; ++kt) {
    int ks = kt * 32 + l4 * 8;
    int hh = ks / 56;
    int rem = ks - hh * 56;
    unsigned aoff = (unsigned)(hh * 336 + rem * 2);
    bf16x8 af[2];
#pragma unroll
    for (int mt = 0; mt < 2; ++mt) {
      int row = mbase + wv * 32 + mt * 16 + l15;
      af[mt] = *(const bf16x8*)(qkvbuf + (size_t)row * 2016 + aoff);
    }
#pragma unroll
    for (int nt = 0; nt < 4; ++nt) {
      bf16x8 pb = *(const bf16x8*)(sm + swzaddr(0, nt * 16 + l15, (kt * 32 + l4 * 8) * 2, 704));
      acc[0][nt] = __builtin_amdgcn_mfma_f32_16x16x32_bf16(af[0], pb, acc[0][nt], 0, 0, 0);
      acc[1][nt] = __builtin_amdgcn_mfma_f32_16x16x32_bf16(af[1], pb, acc[1][nt], 0, 0, 0);
    }
  }
  __syncthreads();

#pragma unroll
  for (int mt = 0; mt < 2; ++mt)
#pragma unroll
    for (int nt = 0; nt < 4; ++nt)
#pragma unroll
      for (int r = 0; r < 4; ++r) {
        int m = wv * 32 + mt * 16 + l4 * 4 + r;
        *(float*)(sm + swzaddr(0, m, (nt * 16 + l15) * 4, 256)) = acc[mt][nt][r];
      }
  __syncthreads();
  for (int jj = tid; jj < 2048; jj += 256) {
    int row = jj >> 4, c = jj & 15;
    uint4 v = *(const uint4*)(sm + swzaddr(0, row, c * 16, 256));
    *(uint4*)((unsigned char*)out + (size_t)(mbase + row) * 768 + nbase * 4 + c * 16) = v;
  }
}

// ==================== FALLBACK PATH (R2 kernel, verbatim) ====================

__global__ void prep_fb(const float* __restrict__ qkv_w,
                        const float* __restrict__ proj_w,
                        const float* __restrict__ tbl,
                        const int* __restrict__ ridx,
                        unsigned char* __restrict__ ws) {
  __hip_bfloat16* qkvwt  = (__hip_bfloat16*)(ws + FB_QKVWT);
  __hip_bfloat16* projwt = (__hip_bfloat16*)(ws + FB_PROJWT);
  float* bias6 = (float*)(ws + FB_BIAS6);
  int idx = blockIdx.x * 256 + threadIdx.x;
  const int n1 = 1008 * 192;
  const int n2 = 192 * 384;
  const int n3 = 6 * 49 * 49;
  if (idx < n1) {
    int c = idx / 192, k = idx - c * 192;
    qkvwt[idx] = __float2bfloat16(qkv_w[k * 1008 + c]);
  } else if (idx < n1 + n2) {
    int j = idx - n1;
    int c = j / 384, kk = j - c * 384;
    projwt[j] = __float2bfloat16(kk < 336 ? proj_w[kk * 192 + c] : 0.0f);
  } else if (idx < n1 + n2 + n3) {
    int j = idx - n1 - n2;
    int h = j / 2401, mn = j - h * 2401;
    bias6[j] = tbl[ridx[mn] * 6 + h];
  }
}

#define QS_OFF  0
#define KS_OFF  8192
#define VT_OFF  16384
#define ATT_OFF 24576
#define SMEM_BYTES 32768

__global__ __launch_bounds__(256, 4) void winattn_fb(
    const float* __restrict__ x, const float* __restrict__ mask,
    const float* __restrict__ qkv_b, const float* __restrict__ lepe_w,
    const float* __restrict__ lepe_b, const float* __restrict__ proj_b,
    const unsigned char* __restrict__ ws, float* __restrict__ out) {
  __shared__ uint4 smem4[SMEM_BYTES / 16];
  unsigned char* sm = (unsigned char*)smem4;
  const __hip_bfloat16* qkvwt  = (const __hip_bfloat16*)(ws + FB_QKVWT);
  const __hip_bfloat16* projwt = (const __hip_bfloat16*)(ws + FB_PROJWT);
  const float* bias6 = (const float*)(ws + FB_BIAS6);

  const int tid = threadIdx.x;
  const int lane = tid & 63, wv = tid >> 6;
  const int l15 = lane & 15, l4 = lane >> 4;
  const int blk = blockIdx.x;
  const int wdx = blk & 63;
  {
    uint4 z = {0u, 0u, 0u, 0u};
    for (int i = tid; i < SMEM_BYTES / 16; i += 256) smem4[i] = z;
  }
  const int arow = wv * 16 + l15;
  const float* xg = x + (size_t)blk * (NTOK * DIMC);
  const int xr = arow < NTOK ? arow : NTOK - 1;
  bf16x8 afr[6];
#pragma unroll
  for (int kt = 0; kt < 6; ++kt) {
    const float4* p = (const float4*)(xg + xr * DIMC + kt * 32 + l4 * 8);
    float4 a = p[0], b = p[1];
    union { unsigned short u[8]; bf16x8 v; } pk;
    pk.u[0] = f2bu(a.x); pk.u[1] = f2bu(a.y); pk.u[2] = f2bu(a.z); pk.u[3] = f2bu(a.w);
    pk.u[4] = f2bu(b.x); pk.u[5] = f2bu(b.y); pk.u[6] = f2bu(b.z); pk.u[7] = f2bu(b.w);
    afr[kt] = pk.v;
  }
  f32x4 pacc[12];
#pragma unroll
  for (int nt = 0; nt < 12; ++nt) {
    float pb = proj_b[nt * 16 + l15];
    pacc[nt] = (f32x4){pb, pb, pb, pb};
  }
  const float* maskw = mask + wdx * (NTOK * NTOK);
  __syncthreads();

  for (int h = 0; h < NH; ++h) {
    for (int i = tid; i < NTOK * NTOK; i += 256) {
      int row = i / NTOK, col = i - row * NTOK;
      *(unsigned short*)(sm + ATT_OFF + row * 128 + col * 2) =
          f2bu(bias6[h * (NTOK * NTOK) + i] + maskw[i]);
    }
#pragma unroll
    for (int nt = 0; nt < 11; ++nt) {
      int cl = nt * 16 + l15;
      int cg = h * 168 + cl; if (cg > 1007) cg = 1007;
      float bias = qkv_b[cg];
      f32x4 acc = (f32x4){bias, bias, bias, bias};
#pragma unroll
      for (int kt = 0; kt < 6; ++kt) {
        bf16x8 bf = *(const bf16x8*)(qkvwt + cg * DIMC + kt * 32 + l4 * 8);
        acc = __builtin_amdgcn_mfma_f32_16x16x32_bf16(afr[kt], bf, acc, 0, 0, 0);
      }
      if (cl < 168) {
#pragma unroll
        for (int r = 0; r < 4; ++r) {
          int m = wv * 16 + l4 * 4 + r;
          if (m < NTOK) {
            float vv = acc[r];
            if (cl < 56)
              *(__hip_bfloat16*)(sm + swzaddr(QS_OFF, m, cl * 2, 128)) = __float2bfloat16(vv);
            else if (cl < 112)
              *(__hip_bfloat16*)(sm + swzaddr(KS_OFF, m, (cl - 56) * 2, 128)) = __float2bfloat16(vv);
            else
              *(__hip_bfloat16*)(sm + swzaddr(VT_OFF, cl - 112, m * 2, 128)) = __float2bfloat16(vv);
          }
        }
      }
    }
    __syncthreads();
    bf16x8 qa[2];
#pragma unroll
    for (int kt = 0; kt < 2; ++kt)
      qa[kt] = *(const bf16x8*)(sm + swzaddr(QS_OFF, arow, (kt * 32 + l4 * 8) * 2, 128));
    f32x4 sv[4];
#pragma unroll
    for (int nt = 0; nt < 4; ++nt) {
      f32x4 acc = (f32x4){0.f, 0.f, 0.f, 0.f};
#pragma unroll
      for (int kt = 0; kt < 2; ++kt) {
        bf16x8 kb = *(const bf16x8*)(sm + swzaddr(KS_OFF, nt * 16 + l15, (kt * 32 + l4 * 8) * 2, 128));
        acc = __builtin_amdgcn_mfma_f32_16x16x32_bf16(qa[kt], kb, acc, 0, 0, 0);
      }
      sv[nt] = acc;
    }
#pragma unroll
    for (int nt = 0; nt < 4; ++nt) {
      int n = nt * 16 + l15;
#pragma unroll
      for (int r = 0; r < 4; ++r) {
        int m = wv * 16 + l4 * 4 + r;
        int mc = m < NTOK ? m : NTOK - 1;
        float vv;
        if (n < NTOK) {
          float add = __bfloat162float(
              *(const __hip_bfloat16*)(sm + ATT_OFF + mc * 128 + n * 2));
          vv = SCALE * sv[nt][r] + add;
        } else {
          vv = -1e30f;
        }
        sv[nt][r] = vv;
      }
    }
#pragma unroll
    for (int r = 0; r < 4; ++r) {
      float mx = fmaxf(fmaxf(sv[0][r], sv[1][r]), fmaxf(sv[2][r], sv[3][r]));
      mx = fmaxf(mx, __shfl_xor(mx, 1));
      mx = fmaxf(mx, __shfl_xor(mx, 2));
      mx = fmaxf(mx, __shfl_xor(mx, 4));
      mx = fmaxf(mx, __shfl_xor(mx, 8));
      float p0 = __expf(sv[0][r] - mx), p1 = __expf(sv[1][r] - mx);
      float p2 = __expf(sv[2][r] - mx), p3 = __expf(sv[3][r] - mx);
      float sum = p0 + p1 + p2 + p3;
      sum += __shfl_xor(sum, 1);
      sum += __shfl_xor(sum, 2);
      sum += __shfl_xor(sum, 4);
      sum += __shfl_xor(sum, 8);
      float rinv = 1.0f / sum;
      sv[0][r] = p0 * rinv; sv[1][r] = p1 * rinv; sv[2][r] = p2 * rinv; sv[3][r] = p3 * rinv;
    }
#pragma unroll
    for (int nt = 0; nt < 4; ++nt) {
      int n = nt * 16 + l15;
#pragma unroll
      for (int r = 0; r < 4; ++r) {
        int m = wv * 16 + l4 * 4 + r;
        if (m < NTOK)
          *(__hip_bfloat16*)(sm + swzaddr(ATT_OFF, m, n * 2, 128)) = __float2bfloat16(sv[nt][r]);
      }
    }
    bf16x8 pa[2];
#pragma unroll
    for (int kt = 0; kt < 2; ++kt)
      pa[kt] = *(const bf16x8*)(sm + swzaddr(ATT_OFF, arow, (kt * 32 + l4 * 8) * 2, 128));
    f32x4 ov[4];
#pragma unroll
    for (int nt = 0; nt < 4; ++nt) {
      f32x4 acc = (f32x4){0.f, 0.f, 0.f, 0.f};
#pragma unroll
      for (int kt = 0; kt < 2; ++kt) {
        bf16x8 vb = *(const bf16x8*)(sm + swzaddr(VT_OFF, nt * 16 + l15, (kt * 32 + l4 * 8) * 2, 128));
        acc = __builtin_amdgcn_mfma_f32_16x16x32_bf16(pa[kt], vb, acc, 0, 0, 0);
      }
      ov[nt] = acc;
    }
#pragma unroll
    for (int nt = 0; nt < 4; ++nt) {
      int d = nt * 16 + l15;
      if (d < HDIM) {
        const float* lw = lepe_w + (h * HDIM + d) * 9;
        float w9[9];
#pragma unroll
        for (int t9 = 0; t9 < 9; ++t9) w9[t9] = lw[t9];
        float lb = lepe_b[h * HDIM + d];
#pragma unroll
        for (int r = 0; r < 4; ++r) {
          int m = wv * 16 + l4 * 4 + r;
          if (m < NTOK) {
            int y = m / 7, x0 = m - y * 7;
            float lac = lb;
#pragma unroll
            for (int dy = 0; dy < 3; ++dy)
#pragma unroll
              for (int dx = 0; dx < 3; ++dx) {
                int yy = y + dy - 1, xx = x0 + dx - 1;
                if (yy >= 0 && yy < 7 && xx >= 0 && xx < 7) {
                  float vvv = __bfloat162float(
                      *(const __hip_bfloat16*)(sm + swzaddr(VT_OFF, d, (yy * 7 + xx) * 2, 128)));
                  lac += w9[dy * 3 + dx] * vvv;
                }
              }
            *(__hip_bfloat16*)(sm + swzaddr(QS_OFF, m, d * 2, 128)) =
                __float2bfloat16(ov[nt][r] + lac);
          }
        }
      }
    }
    bf16x8 oa[2];
#pragma unroll
    for (int kt = 0; kt < 2; ++kt)
      oa[kt] = *(const bf16x8*)(sm + swzaddr(QS_OFF, arow, (kt * 32 + l4 * 8) * 2, 128));
#pragma unroll
    for (int nt = 0; nt < 12; ++nt) {
#pragma unroll
      for (int kt = 0; kt < 2; ++kt) {
        bf16x8 pb = *(const bf16x8*)(projwt + (nt * 16 + l15) * 384 + h * HDIM + kt * 32 + l4 * 8);
        pacc[nt] = __builtin_amdgcn_mfma_f32_16x16x32_bf16(oa[kt], pb, pacc[nt], 0, 0, 0);
      }
    }
    __syncthreads();
  }
  float* og = out + (size_t)blk * (NTOK * DIMC);
#pragma unroll
  for (int nt = 0; nt < 12; ++nt) {
#pragma unroll
    for (int r = 0; r < 4; ++r) {
      int m = wv * 16 + l4 * 4 + r;
      if (m < NTOK) og[m * DIMC + nt * 16 + l15] = pacc[nt][r];
    }
  }
}

// ==================== launcher ====================

extern "C" void kernel_launch(void* const* d_in, const int* in_sizes, int n_in,
                              void* d_out, int out_size, void* d_ws, size_t ws_size,
                              hipStream_t stream) {
  const float* x      = (const float*)d_in[0];
  const float* mask   = (const float*)d_in[1];
  const float* qkv_w  = (const float*)d_in[2];
  const float* qkv_b  = (const float*)d_in[3];
  const float* tbl    = (const float*)d_in[4];
  const int*   ridx   = (const int*)d_in[5];
  const float* lepe_w = (const float*)d_in[6];
  const float* lepe_b = (const float*)d_in[7];
  const float* proj_w = (const float*)d_in[8];
  const float* proj_b = (const float*)d_in[9];
  unsigned char* ws = (unsigned char*)d_ws;
  float* out = (float*)d_out;

  const int n_prep = 1008 * 192 + 192 * 352 + 1008 + 64 * 6 * 64 * 64 + 9 * 336;
  const int prep_blocks = (n_prep + 255) / 256;
  if (ws_size >= WS_NEED2) {
    prep_all<<<dim3(XCVT_BLOCKS + prep_blocks), dim3(256), 0, stream>>>(
        x, qkv_w, qkv_b, proj_w, tbl, ridx, mask, lepe_w, ws);
    qkv_gemm5<<<dim3(10976), dim3(256), 0, stream>>>(ws);
    attn_head<<<dim3(12288), dim3(256), 0, stream>>>(lepe_b, ws);
    proj_gemm<<<dim3(2352), dim3(256), 0, stream>>>(proj_b, ws, out);
  } else if (ws_size >= WS_NEED) {
    prep_main<<<dim3(prep_blocks), dim3(256), 0, stream>>>(
        qkv_w, qkv_b, proj_w, tbl, ridx, mask, lepe_w, ws);
    qkv_gemm<<<dim3(5488), dim3(256), 0, stream>>>(x, ws);
    attn_head<<<dim3(12288), dim3(256), 0, stream>>>(lepe_b, ws);
    proj_gemm<<<dim3(2352), dim3(256), 0, stream>>>(proj_b, ws, out);
  } else {
    prep_fb<<<dim3(1101), dim3(256), 0, stream>>>(qkv_w, proj_w, tbl, ridx, ws);
    winattn_fb<<<dim3(2048), dim3(256), 0, stream>>>(x, mask, qkv_b, lepe_w, lepe_b,
                                                     proj_b, ws, out);
  }
}

// Round 16
// 281.371 us; speedup vs baseline: 1.5620x; 1.5620x over previous
//
#include <hip/hip_runtime.h>
#include <hip/hip_bf16.h>

typedef __bf16 bf16x8 __attribute__((ext_vector_type(8)));
typedef unsigned short u16x8 __attribute__((ext_vector_type(8)));
typedef float f32x4 __attribute__((ext_vector_type(4)));

#define NTOK 49
#define NH   6
#define HDIM 56
#define DIMC 192
#define SCALE 0.17677669529663687f

// ---------------- workspace layout (bytes) ----------------
#define WS_QKVWT   0u          // bf16 [1008][192] transposed qkv_w, q-cols pre-scaled
#define WS_PROJWT  387072u     // bf16 [192][352]  transposed proj_w, K padded 336->352 w/ zeros
#define WS_QKVBS   522240u     // f32  [1008]      qkv_b, q-entries pre-scaled
#define WS_BMALLT  526272u     // bf16 [64][6][64 n][64 m] transposed bias+mask (linear)
#define WS_LEPET   3672000u    // f32  [9][336]    lepe_w transposed (tap-major)
#define WS_QKV     3684288u    // bf16 [100352][1008] qkv activations (q-slot later holds O+lepe)
#define WS_NEED    (WS_QKV + (size_t)100352 * 2016 + 4096)
// tier-1 extras: bf16 copy of x
#define WS_XBF     (WS_QKV + (size_t)100352 * 2016)            // bf16 [100352][192]
#define WS_NEED2   (WS_XBF + (size_t)100352 * 384 + 4096)      // ~245 MB
// fallback path (R2 layout, 591KB):
#define FB_QKVWT  0
#define FB_PROJWT 387072
#define FB_BIAS6  534528

// Full-address XOR swizzle. Safe (globally bijective) for strides that are
// multiples of 128, or ≡64 mod 128.
__device__ __forceinline__ unsigned swzaddr(unsigned base, int row, int colb, int strideb) {
  return base + (unsigned)((row * strideb + colb) ^ ((row & 7) << 4));
}

__device__ __forceinline__ unsigned short f2bu(float f) {
  __hip_bfloat16 h = __float2bfloat16(f);
  unsigned short u;
  __builtin_memcpy(&u, &h, 2);
  return u;
}

__device__ __forceinline__ float bu2f(unsigned short u) {
  union { unsigned int i; float f; } x;
  x.i = ((unsigned int)u) << 16;
  return x.f;
}

// ==================== MAIN PATH ====================

// prep body (idx-parameterized so it can be fused with xcvt)
__device__ __forceinline__ void prep_body(
    int idx,
    const float* __restrict__ qkv_w, const float* __restrict__ qkv_b,
    const float* __restrict__ proj_w, const float* __restrict__ tbl,
    const int* __restrict__ ridx, const float* __restrict__ mask,
    const float* __restrict__ lepe_w, unsigned char* __restrict__ ws) {
  __hip_bfloat16* qkvwt   = (__hip_bfloat16*)(ws + WS_QKVWT);
  __hip_bfloat16* projwt2 = (__hip_bfloat16*)(ws + WS_PROJWT);
  float*          qkvbs   = (float*)(ws + WS_QKVBS);
  __hip_bfloat16* bmallT  = (__hip_bfloat16*)(ws + WS_BMALLT);
  float*          lepeT   = (float*)(ws + WS_LEPET);
  const int n1 = 1008 * 192;        // qkvwt
  const int n2 = 192 * 352;         // projwt2
  const int n3 = 1008;              // qkvbs
  const int n4 = 64 * 6 * 64 * 64;  // bmallT
  const int n5 = 9 * 336;           // lepeT
  if (idx < n1) {
    int c = idx / 192, k = idx - c * 192;
    float v = qkv_w[k * 1008 + c];
    if (c % 168 < 56) v *= SCALE;
    qkvwt[idx] = __float2bfloat16(v);
  } else if (idx < n1 + n2) {
    int j = idx - n1;
    int n = j / 352, kk = j - n * 352;
    projwt2[j] = __float2bfloat16(kk < 336 ? proj_w[kk * 192 + n] : 0.0f);
  } else if (idx < n1 + n2 + n3) {
    int c = idx - n1 - n2;
    float v = qkv_b[c];
    if (c % 168 < 56) v *= SCALE;
    qkvbs[c] = v;
  } else if (idx < n1 + n2 + n3 + n4) {
    int j = idx - n1 - n2 - n3;
    int wh = j >> 12;
    int e = j & 4095;
    int n = e >> 6, m = e & 63;
    int wdx = wh / 6, h = wh - wdx * 6;
    float v;
    if (n >= NTOK) v = -1e30f;
    else if (m >= NTOK) v = 0.0f;
    else v = tbl[ridx[m * NTOK + n] * NH + h] + mask[wdx * (NTOK * NTOK) + m * NTOK + n];
    bmallT[j] = __float2bfloat16(v);
  } else if (idx < n1 + n2 + n3 + n4 + n5) {
    int j = idx - n1 - n2 - n3 - n4;
    int tap = j / 336, hd = j - tap * 336;
    lepeT[j] = lepe_w[hd * 9 + tap];
  }
}

// fused prep + xcvt: blocks [0,9408) convert x->bf16; the rest run prep.
#define XCVT_BLOCKS 9408
__global__ __launch_bounds__(256) void prep_all(
    const float* __restrict__ x,
    const float* __restrict__ qkv_w, const float* __restrict__ qkv_b,
    const float* __restrict__ proj_w, const float* __restrict__ tbl,
    const int* __restrict__ ridx, const float* __restrict__ mask,
    const float* __restrict__ lepe_w, unsigned char* __restrict__ ws) {
  int bid = blockIdx.x;
  if (bid < XCVT_BLOCKS) {
    unsigned char* xbf = ws + WS_XBF;
    int i = bid * 256 + threadIdx.x;
    if (i >= 2408448) return;
    const float4* p = (const float4*)(x + (size_t)i * 8);
    float4 a = p[0], b = p[1];
    union { unsigned short u[8]; uint4 q; } pk;
    pk.u[0] = f2bu(a.x); pk.u[1] = f2bu(a.y); pk.u[2] = f2bu(a.z); pk.u[3] = f2bu(a.w);
    pk.u[4] = f2bu(b.x); pk.u[5] = f2bu(b.y); pk.u[6] = f2bu(b.z); pk.u[7] = f2bu(b.w);
    *(uint4*)(xbf + (size_t)i * 16) = pk.q;
  } else {
    int idx = (bid - XCVT_BLOCKS) * 256 + threadIdx.x;
    prep_body(idx, qkv_w, qkv_b, proj_w, tbl, ridx, mask, lepe_w, ws);
  }
}

// tier-2 prep (no xcvt)
__global__ void prep_main(const float* __restrict__ qkv_w,
                          const float* __restrict__ qkv_b,
                          const float* __restrict__ proj_w,
                          const float* __restrict__ tbl,
                          const int* __restrict__ ridx,
                          const float* __restrict__ mask,
                          const float* __restrict__ lepe_w,
                          unsigned char* __restrict__ ws) {
  prep_body(blockIdx.x * 256 + threadIdx.x, qkv_w, qkv_b, proj_w, tbl, ridx, mask,
            lepe_w, ws);
}

// K1 (tier-1, R14-best): qkv = xbf @ Wqkv + b. BM=64, BN=144, K staged in 3
// thirds of 64 cols ([144][64el] @128B stride, 18432B). LDS alloc 20480B.
// NOTE: R15's register-prefetch pipeline variant SPILLED (guarded uint4[5]
// array -> scratch; WRITE_SIZE 198->771MB, 2.4x slower). Keep this simple form.
__global__ __launch_bounds__(256, 2) void qkv_gemm5(unsigned char* __restrict__ ws) {
  __shared__ uint4 smem4[1280];   // 20480 B
  unsigned char* sm = (unsigned char*)smem4;
  const unsigned char* qkvwtb = ws + WS_QKVWT;
  const float* qkvbs = (const float*)(ws + WS_QKVBS);
  const unsigned char* xbf = ws + WS_XBF;
  unsigned char* qkvbuf = ws + WS_QKV;

  const int tid = threadIdx.x;
  const int lane = tid & 63, wv = tid >> 6;
  const int l15 = lane & 15, l4 = lane >> 4;
  const int b = blockIdx.x;
  const int j = (b & 7) * 1372 + (b >> 3);   // 10976 = 8*1372
  const int nbase = (j % 7) * 144;
  const int mbase = (j / 7) * 64;

  f32x4 acc[9];
#pragma unroll
  for (int nt = 0; nt < 9; ++nt) {
    float bb = qkvbs[nbase + nt * 16 + l15];
    acc[nt] = (f32x4){bb, bb, bb, bb};
  }
  const unsigned char* xrow = xbf + (size_t)(mbase + wv * 16 + l15) * 384;

#pragma unroll
  for (int t = 0; t < 3; ++t) {
    if (t) __syncthreads();
    // stage B third: rows [nbase,nbase+144), cols [t*64, t*64+64) elements
    for (int jj = tid; jj < 1152; jj += 256) {
      int row = jj >> 3, c16 = jj & 7;
      uint4 v = *(const uint4*)(qkvwtb + (size_t)(nbase + row) * 384 + t * 128 + c16 * 16);
      *(uint4*)(sm + swzaddr(0, row, c16 * 16, 128)) = v;
    }
    bf16x8 afr0 = *(const bf16x8*)(xrow + t * 128 + l4 * 16);
    bf16x8 afr1 = *(const bf16x8*)(xrow + t * 128 + 64 + l4 * 16);
    __syncthreads();
#pragma unroll
    for (int kt2 = 0; kt2 < 2; ++kt2) {
      bf16x8 a = kt2 ? afr1 : afr0;
#pragma unroll
      for (int nt = 0; nt < 9; ++nt) {
        bf16x8 bf = *(const bf16x8*)(sm + swzaddr(0, nt * 16 + l15, kt2 * 64 + l4 * 16, 128));
        acc[nt] = __builtin_amdgcn_mfma_f32_16x16x32_bf16(a, bf, acc[nt], 0, 0, 0);
      }
    }
  }
  __syncthreads();

  // dump C (bf16) into LDS [64 rows]@stride 320, coalesced copy-out
#pragma unroll
  for (int nt = 0; nt < 9; ++nt)
#pragma unroll
    for (int r = 0; r < 4; ++r) {
      int row = wv * 16 + l4 * 4 + r;
      *(unsigned short*)(sm + swzaddr(0, row, (nt * 16 + l15) * 2, 320)) = f2bu(acc[nt][r]);
    }
  __syncthreads();
  for (int jj = tid; jj < 1152; jj += 256) {
    int row = jj / 18, c16 = jj - row * 18;
    uint4 v = *(const uint4*)(sm + swzaddr(0, row, c16 * 16, 320));
    *(uint4*)(qkvbuf + (size_t)(mbase + row) * 2016 + nbase * 2 + c16 * 16) = v;
  }
}

// K1 (tier-2): qkv from fp32 x with in-kernel cvt. BM=128.
__global__ __launch_bounds__(256, 2) void qkv_gemm(
    const float* __restrict__ x, unsigned char* __restrict__ ws) {
  __shared__ uint4 smem4[2560];   // 40960 B
  unsigned char* sm = (unsigned char*)smem4;
  const __hip_bfloat16* qkvwt = (const __hip_bfloat16*)(ws + WS_QKVWT);
  const float* qkvbs = (const float*)(ws + WS_QKVBS);
  unsigned char* qkvbuf = ws + WS_QKV;

  const int tid = threadIdx.x;
  const int lane = tid & 63, wv = tid >> 6;
  const int l15 = lane & 15, l4 = lane >> 4;
  const int b = blockIdx.x;
  const int j = (b & 7) * 686 + (b >> 3);     // 5488 = 8*686
  const int nbase = (j % 7) * 144;
  const int mbase = (j / 7) * 128;

  bf16x8 afr[2][6];
#pragma unroll
  for (int mt = 0; mt < 2; ++mt) {
    int g = mbase + wv * 32 + mt * 16 + l15;
    const float* xr = x + (size_t)g * DIMC;
#pragma unroll
    for (int kt = 0; kt < 6; ++kt) {
      const float4* p = (const float4*)(xr + kt * 32 + l4 * 8);
      float4 a = p[0], bb = p[1];
      union { unsigned short u[8]; bf16x8 v; } pk;
      pk.u[0] = f2bu(a.x); pk.u[1] = f2bu(a.y); pk.u[2] = f2bu(a.z); pk.u[3] = f2bu(a.w);
      pk.u[4] = f2bu(bb.x); pk.u[5] = f2bu(bb.y); pk.u[6] = f2bu(bb.z); pk.u[7] = f2bu(bb.w);
      afr[mt][kt] = pk.v;
    }
  }

  f32x4 acc[2][9];
#pragma unroll
  for (int nt = 0; nt < 9; ++nt) {
    float bb = qkvbs[nbase + nt * 16 + l15];
    acc[0][nt] = (f32x4){bb, bb, bb, bb};
    acc[1][nt] = (f32x4){bb, bb, bb, bb};
  }

#pragma unroll
  for (int kh = 0; kh < 2; ++kh) {
    if (kh) __syncthreads();
    for (int jj = tid; jj < 1728; jj += 256) {
      int row = jj / 12, c16 = jj - row * 12;
      uint4 v = *(const uint4*)((const unsigned char*)qkvwt +
                                (size_t)(nbase + row) * 384 + kh * 192 + c16 * 16);
      *(uint4*)(sm + swzaddr(0, row, c16 * 16, 256)) = v;
    }
    __syncthreads();
#pragma unroll
    for (int kt2 = 0; kt2 < 3; ++kt2) {
      const int kt = kh * 3 + kt2;
#pragma unroll
      for (int nt = 0; nt < 9; ++nt) {
        bf16x8 bf = *(const bf16x8*)(sm + swzaddr(0, nt * 16 + l15, kt2 * 64 + l4 * 16, 256));
        acc[0][nt] = __builtin_amdgcn_mfma_f32_16x16x32_bf16(afr[0][kt], bf, acc[0][nt], 0, 0, 0);
        acc[1][nt] = __builtin_amdgcn_mfma_f32_16x16x32_bf16(afr[1][kt], bf, acc[1][nt], 0, 0, 0);
      }
    }
  }
  __syncthreads();

#pragma unroll
  for (int mt = 0; mt < 2; ++mt)
#pragma unroll
    for (int nt = 0; nt < 9; ++nt)
#pragma unroll
      for (int r = 0; r < 4; ++r) {
        int row = wv * 32 + mt * 16 + l4 * 4 + r;
        *(unsigned short*)(sm + swzaddr(0, row, (nt * 16 + l15) * 2, 320)) =
            f2bu(acc[mt][nt][r]);
      }
  __syncthreads();
  for (int jj = tid; jj < 2304; jj += 256) {
    int row = jj / 18, c16 = jj - row * 18;
    uint4 v = *(const uint4*)(sm + swzaddr(0, row, c16 * 16, 320));
    *(uint4*)(qkvbuf + (size_t)(mbase + row) * 2016 + nbase * 2 + c16 * 16) = v;
  }
}

// K2 (R11-best variant, 123us measured): one block per (head, window),
// XCD-swizzled. LDS 32K: KS 8K (k, then P after barrier; O-dump overlays
// KS+VT) | VT 8K | VS 16K (v as f32 [64][64]@256B). bias+mask read direct
// from global (L2-hot).
#define A_KS   0u
#define A_VT   8192u
#define A_VS   16384u
#define A_SMEM 32768u

__global__ __launch_bounds__(256, 4) void attn_head(
    const float* __restrict__ lepe_b, unsigned char* __restrict__ ws) {
  __shared__ uint4 smem4[A_SMEM / 16];
  unsigned char* sm = (unsigned char*)smem4;
  const unsigned char* bmallT = ws + WS_BMALLT;
  const float* lepeT = (const float*)(ws + WS_LEPET);
  unsigned char* qkvbuf = ws + WS_QKV;

  const int tid = threadIdx.x;
  const int lane = tid & 63, wv = tid >> 6;
  const int l15 = lane & 15, l4 = lane >> 4;
  const int b = blockIdx.x;
  const int j = (b & 7) * 1536 + (b >> 3);    // 12288 = 8*1536
  const int h = j % 6;
  const int win = j / 6;
  const int wdx = win & 63;
  unsigned char* qbase = qkvbuf + (size_t)win * (NTOK * 2016);

  const int arow = wv * 16 + l15;
  const int xr = arow < NTOK ? arow : NTOK - 1;
  const int mc0 = wv * 16 + l4 * 4;

  // early independent global loads: q fragments + bias/mask rows (L2-hot 3MB table)
  bf16x8 qa[2];
#pragma unroll
  for (int kt = 0; kt < 2; ++kt)
    qa[kt] = *(const bf16x8*)(qbase + (size_t)xr * 2016 + h * 336 + kt * 64 + l4 * 16);
  unsigned long long bm8[4];
  {
    const unsigned char* bmrow = bmallT + (size_t)(wdx * NH + h) * 8192;
#pragma unroll
    for (int nt = 0; nt < 4; ++nt)
      bm8[nt] = *(const unsigned long long*)(bmrow + (nt * 16 + l15) * 128 + mc0 * 2);
  }

  // zero KS+VT (16KB): pads feed MFMA B-operands, must be exact 0.
  {
    uint4 z = {0u, 0u, 0u, 0u};
    for (int i = tid; i < 1024; i += 256) smem4[i] = z;
  }
  __syncthreads();

  // stage k (KS swizzled), v transposed (VT), v as f32 (VS); m-major lane map
  for (int jj = tid; jj < 343; jj += 256) {
    int m = jj % 49, c = jj / 49;
    const unsigned char* row = qbase + (size_t)m * 2016 + h * 336;
    uint4 kv = *(const uint4*)(row + 112 + c * 16);
    *(uint4*)(sm + swzaddr(A_KS, m, c * 16, 128)) = kv;
    uint4 vv = *(const uint4*)(row + 224 + c * 16);
    union { uint4 q; unsigned short u[8]; } pk; pk.q = vv;
#pragma unroll
    for (int e = 0; e < 8; ++e)
      *(unsigned short*)(sm + swzaddr(A_VT, c * 8 + e, m * 2, 128)) = pk.u[e];
    float4 vf0, vf1;
    vf0.x = bu2f(pk.u[0]); vf0.y = bu2f(pk.u[1]); vf0.z = bu2f(pk.u[2]); vf0.w = bu2f(pk.u[3]);
    vf1.x = bu2f(pk.u[4]); vf1.y = bu2f(pk.u[5]); vf1.z = bu2f(pk.u[6]); vf1.w = bu2f(pk.u[7]);
    *(float4*)(sm + swzaddr(A_VS, m, c * 32, 256)) = vf0;
    *(float4*)(sm + swzaddr(A_VS, m, c * 32 + 16, 256)) = vf1;
  }
  __syncthreads();

  // ---- S = (bias+mask) + q k^T ----
  f32x4 sv[4];
#pragma unroll
  for (int nt = 0; nt < 4; ++nt) {
#pragma unroll
    for (int r = 0; r < 4; ++r)
      sv[nt][r] = bu2f((unsigned short)(bm8[nt] >> (16 * r)));
    int n = nt * 16 + l15;
#pragma unroll
    for (int kt = 0; kt < 2; ++kt) {
      bf16x8 kb = *(const bf16x8*)(sm + swzaddr(A_KS, n, kt * 64 + l4 * 16, 128));
      sv[nt] = __builtin_amdgcn_mfma_f32_16x16x32_bf16(qa[kt], kb, sv[nt], 0, 0, 0);
    }
  }

  // ---- softmax over rows ----
#pragma unroll
  for (int r = 0; r < 4; ++r) {
    float mx = fmaxf(fmaxf(sv[0][r], sv[1][r]), fmaxf(sv[2][r], sv[3][r]));
    mx = fmaxf(mx, __shfl_xor(mx, 1));
    mx = fmaxf(mx, __shfl_xor(mx, 2));
    mx = fmaxf(mx, __shfl_xor(mx, 4));
    mx = fmaxf(mx, __shfl_xor(mx, 8));
    float p0 = __expf(sv[0][r] - mx), p1 = __expf(sv[1][r] - mx);
    float p2 = __expf(sv[2][r] - mx), p3 = __expf(sv[3][r] - mx);
    float sum = p0 + p1 + p2 + p3;
    sum += __shfl_xor(sum, 1);
    sum += __shfl_xor(sum, 2);
    sum += __shfl_xor(sum, 4);
    sum += __shfl_xor(sum, 8);
    float rinv = __builtin_amdgcn_rcpf(sum);
    sv[0][r] = p0 * rinv; sv[1][r] = p1 * rinv; sv[2][r] = p2 * rinv; sv[3][r] = p3 * rinv;
  }

  // all waves done reading KS -> safe to overwrite with P
  __syncthreads();
#pragma unroll
  for (int nt = 0; nt < 4; ++nt) {
    int n = nt * 16 + l15;
#pragma unroll
    for (int r = 0; r < 4; ++r) {
      int m = mc0 + r;
      if (m < NTOK)
        *(__hip_bfloat16*)(sm + swzaddr(A_KS, m, n * 2, 128)) = __float2bfloat16(sv[nt][r]);
    }
  }
  // pad rows 49..63 of KS still hold 0 from the initial zeroing; pad cols n>=49
  // hold exp(-1e30)=0 written above -> P pads exact 0.

  // ---- O = P @ V ----
  bf16x8 pa[2];
#pragma unroll
  for (int kt = 0; kt < 2; ++kt)
    pa[kt] = *(const bf16x8*)(sm + swzaddr(A_KS, arow, kt * 64 + l4 * 16, 128));
  f32x4 ov[4];
#pragma unroll
  for (int nt = 0; nt < 4; ++nt) {
    f32x4 a0 = (f32x4){0.f, 0.f, 0.f, 0.f};
#pragma unroll
    for (int kt = 0; kt < 2; ++kt) {
      bf16x8 vb = *(const bf16x8*)(sm + swzaddr(A_VT, nt * 16 + l15, kt * 64 + l4 * 16, 128));
      a0 = __builtin_amdgcn_mfma_f32_16x16x32_bf16(pa[kt], vb, a0, 0, 0, 0);
    }
    ov[nt] = a0;
  }

  // ---- dump O (f32) into KS+VT region (dead after PV) ----
  __syncthreads();
#pragma unroll
  for (int nt = 0; nt < 4; ++nt) {
    int d = nt * 16 + l15;
#pragma unroll
    for (int r = 0; r < 4; ++r) {
      int m = mc0 + r;
      *(float*)(sm + swzaddr(0, m, d * 4, 256)) = ov[nt][r];
    }
  }
  __syncthreads();

  // ---- fused: out[m][d0..d0+7] = O + lepe (VS f32, weights from L2) ----
  for (int jj = tid; jj < 343; jj += 256) {
    int m = jj % 49, c = jj / 49;
    int y = m / 7, x0 = m - y * 7;
    float4 a0 = *(const float4*)(sm + swzaddr(0, m, c * 32, 256));
    float4 a1 = *(const float4*)(sm + swzaddr(0, m, c * 32 + 16, 256));
    const float4* lb = (const float4*)(lepe_b + h * HDIM + c * 8);
    float4 b0 = lb[0], b1 = lb[1];
    a0.x += b0.x; a0.y += b0.y; a0.z += b0.z; a0.w += b0.w;
    a1.x += b1.x; a1.y += b1.y; a1.z += b1.z; a1.w += b1.w;
#pragma unroll
    for (int dy = 0; dy < 3; ++dy) {
      int yy = y + dy - 1;
      if (yy < 0 || yy >= 7) continue;
#pragma unroll
      for (int dx = 0; dx < 3; ++dx) {
        int xx = x0 + dx - 1;
        if (xx < 0 || xx >= 7) continue;
        int mp = yy * 7 + xx;
        float4 v0 = *(const float4*)(sm + swzaddr(A_VS, mp, c * 32, 256));
        float4 v1 = *(const float4*)(sm + swzaddr(A_VS, mp, c * 32 + 16, 256));
        const float4* wr = (const float4*)(lepeT + (dy * 3 + dx) * 336 + h * HDIM + c * 8);
        float4 w0 = wr[0], w1 = wr[1];
        a0.x += w0.x * v0.x; a0.y += w0.y * v0.y; a0.z += w0.z * v0.z; a0.w += w0.w * v0.w;
        a1.x += w1.x * v1.x; a1.y += w1.y * v1.y; a1.z += w1.z * v1.z; a1.w += w1.w * v1.w;
      }
    }
    union { unsigned short u[8]; uint4 q; } st;
    st.u[0] = f2bu(a0.x); st.u[1] = f2bu(a0.y); st.u[2] = f2bu(a0.z); st.u[3] = f2bu(a0.w);
    st.u[4] = f2bu(a1.x); st.u[5] = f2bu(a1.y); st.u[6] = f2bu(a1.z); st.u[7] = f2bu(a1.w);
    *(uint4*)(qbase + (size_t)m * 2016 + h * 336 + c * 16) = st.q;
  }
}

// K3: out = O @ projwt2 + b. XCD-swizzled.
__global__ __launch_bounds__(256, 3) void proj_gemm(
    const float* __restrict__ proj_b, unsigned char* __restrict__ ws,
    float* __restrict__ out) {
  __shared__ uint4 smem4[2816];   // 45056 B
  unsigned char* sm = (unsigned char*)smem4;
  const unsigned char* projwt2 = ws + WS_PROJWT;
  const unsigned char* qkvbuf = ws + WS_QKV;

  const int tid = threadIdx.x;
  const int lane = tid & 63, wv = tid >> 6;
  const int l15 = lane & 15, l4 = lane >> 4;
  const int b = blockIdx.x;
  const int j = (b & 7) * 294 + (b >> 3);     // 2352 = 8*294
  const int nbase = (j % 3) * 64;
  const int mbase = (j / 3) * 128;

  for (int jj = tid; jj < 2816; jj += 256) {
    int n = jj / 44, c = jj - n * 44;
    uint4 v = *(const uint4*)(projwt2 + (size_t)(nbase + n) * 704 + c * 16);
    *(uint4*)(sm + swzaddr(0, n, c * 16, 704)) = v;
  }
  f32x4 acc[2][4];
#pragma unroll
  for (int nt = 0; nt < 4; ++nt) {
    float bb = proj_b[nbase + nt * 16 + l15];
    acc[0][nt] = (f32x4){bb, bb, bb, bb};
    acc[1][nt] = (f32x4){bb, bb, bb, bb};
  }
  __syncthreads();

  for (int kt = 0; kt < 11; ++kt) {
    int ks = kt * 32 + l4 * 8;
    int hh = ks / 56;
    int rem = ks - hh * 56;
    unsigned aoff = (unsigned)(hh * 336 + rem * 2);
    bf16x8 af[2];
#pragma unroll
    for (int mt = 0; mt < 2; ++mt) {
      int row = mbase + wv * 32 + mt * 16 + l15;
      af[mt] = *(const bf16x8*)(qkvbuf + (size_t)row * 2016 + aoff);
    }
#pragma unroll
    for (int nt = 0; nt < 4; ++nt) {
      bf16x8 pb = *(const bf16x8*)(sm + swzaddr(0, nt * 16 + l15, (kt * 32 + l4 * 8) * 2, 704));
      acc[0][nt] = __builtin_amdgcn_mfma_f32_16x16x32_bf16(af[0], pb, acc[0][nt], 0, 0, 0);
      acc[1][nt] = __builtin_amdgcn_mfma_f32_16x16x32_bf16(af[1], pb, acc[1][nt], 0, 0, 0);
    }
  }
  __syncthreads();

#pragma unroll
  for (int mt = 0; mt < 2; ++mt)
#pragma unroll
    for (int nt = 0; nt < 4; ++nt)
#pragma unroll
      for (int r = 0; r < 4; ++r) {
        int m = wv * 32 + mt * 16 + l4 * 4 + r;
        *(float*)(sm + swzaddr(0, m, (nt * 16 + l15) * 4, 256)) = acc[mt][nt][r];
      }
  __syncthreads();
  for (int jj = tid; jj < 2048; jj += 256) {
    int row = jj >> 4, c = jj & 15;
    uint4 v = *(const uint4*)(sm + swzaddr(0, row, c * 16, 256));
    *(uint4*)((unsigned char*)out + (size_t)(mbase + row) * 768 + nbase * 4 + c * 16) = v;
  }
}

// ==================== FALLBACK PATH (R2 kernel, verbatim) ====================

__global__ void prep_fb(const float* __restrict__ qkv_w,
                        const float* __restrict__ proj_w,
                        const float* __restrict__ tbl,
                        const int* __restrict__ ridx,
                        unsigned char* __restrict__ ws) {
  __hip_bfloat16* qkvwt  = (__hip_bfloat16*)(ws + FB_QKVWT);
  __hip_bfloat16* projwt = (__hip_bfloat16*)(ws + FB_PROJWT);
  float* bias6 = (float*)(ws + FB_BIAS6);
  int idx = blockIdx.x * 256 + threadIdx.x;
  const int n1 = 1008 * 192;
  const int n2 = 192 * 384;
  const int n3 = 6 * 49 * 49;
  if (idx < n1) {
    int c = idx / 192, k = idx - c * 192;
    qkvwt[idx] = __float2bfloat16(qkv_w[k * 1008 + c]);
  } else if (idx < n1 + n2) {
    int j = idx - n1;
    int c = j / 384, kk = j - c * 384;
    projwt[j] = __float2bfloat16(kk < 336 ? proj_w[kk * 192 + c] : 0.0f);
  } else if (idx < n1 + n2 + n3) {
    int j = idx - n1 - n2;
    int h = j / 2401, mn = j - h * 2401;
    bias6[j] = tbl[ridx[mn] * 6 + h];
  }
}

#define QS_OFF  0
#define KS_OFF  8192
#define VT_OFF  16384
#define ATT_OFF 24576
#define SMEM_BYTES 32768

__global__ __launch_bounds__(256, 4) void winattn_fb(
    const float* __restrict__ x, const float* __restrict__ mask,
    const float* __restrict__ qkv_b, const float* __restrict__ lepe_w,
    const float* __restrict__ lepe_b, const float* __restrict__ proj_b,
    const unsigned char* __restrict__ ws, float* __restrict__ out) {
  __shared__ uint4 smem4[SMEM_BYTES / 16];
  unsigned char* sm = (unsigned char*)smem4;
  const __hip_bfloat16* qkvwt  = (const __hip_bfloat16*)(ws + FB_QKVWT);
  const __hip_bfloat16* projwt = (const __hip_bfloat16*)(ws + FB_PROJWT);
  const float* bias6 = (const float*)(ws + FB_BIAS6);

  const int tid = threadIdx.x;
  const int lane = tid & 63, wv = tid >> 6;
  const int l15 = lane & 15, l4 = lane >> 4;
  const int blk = blockIdx.x;
  const int wdx = blk & 63;
  {
    uint4 z = {0u, 0u, 0u, 0u};
    for (int i = tid; i < SMEM_BYTES / 16; i += 256) smem4[i] = z;
  }
  const int arow = wv * 16 + l15;
  const float* xg = x + (size_t)blk * (NTOK * DIMC);
  const int xr = arow < NTOK ? arow : NTOK - 1;
  bf16x8 afr[6];
#pragma unroll
  for (int kt = 0; kt < 6; ++kt) {
    const float4* p = (const float4*)(xg + xr * DIMC + kt * 32 + l4 * 8);
    float4 a = p[0], b = p[1];
    union { unsigned short u[8]; bf16x8 v; } pk;
    pk.u[0] = f2bu(a.x); pk.u[1] = f2bu(a.y); pk.u[2] = f2bu(a.z); pk.u[3] = f2bu(a.w);
    pk.u[4] = f2bu(b.x); pk.u[5] = f2bu(b.y); pk.u[6] = f2bu(b.z); pk.u[7] = f2bu(b.w);
    afr[kt] = pk.v;
  }
  f32x4 pacc[12];
#pragma unroll
  for (int nt = 0; nt < 12; ++nt) {
    float pb = proj_b[nt * 16 + l15];
    pacc[nt] = (f32x4){pb, pb, pb, pb};
  }
  const float* maskw = mask + wdx * (NTOK * NTOK);
  __syncthreads();

  for (int h = 0; h < NH; ++h) {
    for (int i = tid; i < NTOK * NTOK; i += 256) {
      int row = i / NTOK, col = i - row * NTOK;
      *(unsigned short*)(sm + ATT_OFF + row * 128 + col * 2) =
          f2bu(bias6[h * (NTOK * NTOK) + i] + maskw[i]);
    }
#pragma unroll
    for (int nt = 0; nt < 11; ++nt) {
      int cl = nt * 16 + l15;
      int cg = h * 168 + cl; if (cg > 1007) cg = 1007;
      float bias = qkv_b[cg];
      f32x4 acc = (f32x4){bias, bias, bias, bias};
#pragma unroll
      for (int kt = 0; kt < 6; ++kt) {
        bf16x8 bf = *(const bf16x8*)(qkvwt + cg * DIMC + kt * 32 + l4 * 8);
        acc = __builtin_amdgcn_mfma_f32_16x16x32_bf16(afr[kt], bf, acc, 0, 0, 0);
      }
      if (cl < 168) {
#pragma unroll
        for (int r = 0; r < 4; ++r) {
          int m = wv * 16 + l4 * 4 + r;
          if (m < NTOK) {
            float vv = acc[r];
            if (cl < 56)
              *(__hip_bfloat16*)(sm + swzaddr(QS_OFF, m, cl * 2, 128)) = __float2bfloat16(vv);
            else if (cl < 112)
              *(__hip_bfloat16*)(sm + swzaddr(KS_OFF, m, (cl - 56) * 2, 128)) = __float2bfloat16(vv);
            else
              *(__hip_bfloat16*)(sm + swzaddr(VT_OFF, cl - 112, m * 2, 128)) = __float2bfloat16(vv);
          }
        }
      }
    }
    __syncthreads();
    bf16x8 qa[2];
#pragma unroll
    for (int kt = 0; kt < 2; ++kt)
      qa[kt] = *(const bf16x8*)(sm + swzaddr(QS_OFF, arow, (kt * 32 + l4 * 8) * 2, 128));
    f32x4 sv[4];
#pragma unroll
    for (int nt = 0; nt < 4; ++nt) {
      f32x4 acc = (f32x4){0.f, 0.f, 0.f, 0.f};
#pragma unroll
      for (int kt = 0; kt < 2; ++kt) {
        bf16x8 kb = *(const bf16x8*)(sm + swzaddr(KS_OFF, nt * 16 + l15, (kt * 32 + l4 * 8) * 2, 128));
        acc = __builtin_amdgcn_mfma_f32_16x16x32_bf16(qa[kt], kb, acc, 0, 0, 0);
      }
      sv[nt] = acc;
    }
#pragma unroll
    for (int nt = 0; nt < 4; ++nt) {
      int n = nt * 16 + l15;
#pragma unroll
      for (int r = 0; r < 4; ++r) {
        int m = wv * 16 + l4 * 4 + r;
        int mc = m < NTOK ? m : NTOK - 1;
        float vv;
        if (n < NTOK) {
          float add = __bfloat162float(
              *(const __hip_bfloat16*)(sm + ATT_OFF + mc * 128 + n * 2));
          vv = SCALE * sv[nt][r] + add;
        } else {
          vv = -1e30f;
        }
        sv[nt][r] = vv;
      }
    }
#pragma unroll
    for (int r = 0; r < 4; ++r) {
      float mx = fmaxf(fmaxf(sv[0][r], sv[1][r]), fmaxf(sv[2][r], sv[3][r]));
      mx = fmaxf(mx, __shfl_xor(mx, 1));
      mx = fmaxf(mx, __shfl_xor(mx, 2));
      mx = fmaxf(mx, __shfl_xor(mx, 4));
      mx = fmaxf(mx, __shfl_xor(mx, 8));
      float p0 = __expf(sv[0][r] - mx), p1 = __expf(sv[1][r] - mx);
      float p2 = __expf(sv[2][r] - mx), p3 = __expf(sv[3][r] - mx);
      float sum = p0 + p1 + p2 + p3;
      sum += __shfl_xor(sum, 1);
      sum += __shfl_xor(sum, 2);
      sum += __shfl_xor(sum, 4);
      sum += __shfl_xor(sum, 8);
      float rinv = 1.0f / sum;
      sv[0][r] = p0 * rinv; sv[1][r] = p1 * rinv; sv[2][r] = p2 * rinv; sv[3][r] = p3 * rinv;
    }
#pragma unroll
    for (int nt = 0; nt < 4; ++nt) {
      int n = nt * 16 + l15;
#pragma unroll
      for (int r = 0; r < 4; ++r) {
        int m = wv * 16 + l4 * 4 + r;
        if (m < NTOK)
          *(__hip_bfloat16*)(sm + swzaddr(ATT_OFF, m, n * 2, 128)) = __float2bfloat16(sv[nt][r]);
      }
    }
    bf16x8 pa[2];
#pragma unroll
    for (int kt = 0; kt < 2; ++kt)
      pa[kt] = *(const bf16x8*)(sm + swzaddr(ATT_OFF, arow, (kt * 32 + l4 * 8) * 2, 128));
    f32x4 ov[4];
#pragma unroll
    for (int nt = 0; nt < 4; ++nt) {
      f32x4 acc = (f32x4){0.f, 0.f, 0.f, 0.f};
#pragma unroll
      for (int kt = 0; kt < 2; ++kt) {
        bf16x8 vb = *(const bf16x8*)(sm + swzaddr(VT_OFF, nt * 16 + l15, (kt * 32 + l4 * 8) * 2, 128));
        acc = __builtin_amdgcn_mfma_f32_16x16x32_bf16(pa[kt], vb, acc, 0, 0, 0);
      }
      ov[nt] = acc;
    }
#pragma unroll
    for (int nt = 0; nt < 4; ++nt) {
      int d = nt * 16 + l15;
      if (d < HDIM) {
        const float* lw = lepe_w + (h * HDIM + d) * 9;
        float w9[9];
#pragma unroll
        for (int t9 = 0; t9 < 9; ++t9) w9[t9] = lw[t9];
        float lb = lepe_b[h * HDIM + d];
#pragma unroll
        for (int r = 0; r < 4; ++r) {
          int m = wv * 16 + l4 * 4 + r;
          if (m < NTOK) {
            int y = m / 7, x0 = m - y * 7;
            float lac = lb;
#pragma unroll
            for (int dy = 0; dy < 3; ++dy)
#pragma unroll
              for (int dx = 0; dx < 3; ++dx) {
                int yy = y + dy - 1, xx = x0 + dx - 1;
                if (yy >= 0 && yy < 7 && xx >= 0 && xx < 7) {
                  float vvv = __bfloat162float(
                      *(const __hip_bfloat16*)(sm + swzaddr(VT_OFF, d, (yy * 7 + xx) * 2, 128)));
                  lac += w9[dy * 3 + dx] * vvv;
                }
              }
            *(__hip_bfloat16*)(sm + swzaddr(QS_OFF, m, d * 2, 128)) =
                __float2bfloat16(ov[nt][r] + lac);
          }
        }
      }
    }
    bf16x8 oa[2];
#pragma unroll
    for (int kt = 0; kt < 2; ++kt)
      oa[kt] = *(const bf16x8*)(sm + swzaddr(QS_OFF, arow, (kt * 32 + l4 * 8) * 2, 128));
#pragma unroll
    for (int nt = 0; nt < 12; ++nt) {
#pragma unroll
      for (int kt = 0; kt < 2; ++kt) {
        bf16x8 pb = *(const bf16x8*)(projwt + (nt * 16 + l15) * 384 + h * HDIM + kt * 32 + l4 * 8);
        pacc[nt] = __builtin_amdgcn_mfma_f32_16x16x32_bf16(oa[kt], pb, pacc[nt], 0, 0, 0);
      }
    }
    __syncthreads();
  }
  float* og = out + (size_t)blk * (NTOK * DIMC);
#pragma unroll
  for (int nt = 0; nt < 12; ++nt) {
#pragma unroll
    for (int r = 0; r < 4; ++r) {
      int m = wv * 16 + l4 * 4 + r;
      if (m < NTOK) og[m * DIMC + nt * 16 + l15] = pacc[nt][r];
    }
  }
}

// ==================== launcher ====================

extern "C" void kernel_launch(void* const* d_in, const int* in_sizes, int n_in,
                              void* d_out, int out_size, void* d_ws, size_t ws_size,
                              hipStream_t stream) {
  const float* x      = (const float*)d_in[0];
  const float* mask   = (const float*)d_in[1];
  const float* qkv_w  = (const float*)d_in[2];
  const float* qkv_b  = (const float*)d_in[3];
  const float* tbl    = (const float*)d_in[4];
  const int*   ridx   = (const int*)d_in[5];
  const float* lepe_w = (const float*)d_in[6];
  const float* lepe_b = (const float*)d_in[7];
  const float* proj_w = (const float*)d_in[8];
  const float* proj_b = (const float*)d_in[9];
  unsigned char* ws = (unsigned char*)d_ws;
  float* out = (float*)d_out;

  const int n_prep = 1008 * 192 + 192 * 352 + 1008 + 64 * 6 * 64 * 64 + 9 * 336;
  const int prep_blocks = (n_prep + 255) / 256;
  if (ws_size >= WS_NEED2) {
    prep_all<<<dim3(XCVT_BLOCKS + prep_blocks), dim3(256), 0, stream>>>(
        x, qkv_w, qkv_b, proj_w, tbl, ridx, mask, lepe_w, ws);
    qkv_gemm5<<<dim3(10976), dim3(256), 0, stream>>>(ws);
    attn_head<<<dim3(12288), dim3(256), 0, stream>>>(lepe_b, ws);
    proj_gemm<<<dim3(2352), dim3(256), 0, stream>>>(proj_b, ws, out);
  } else if (ws_size >= WS_NEED) {
    prep_main<<<dim3(prep_blocks), dim3(256), 0, stream>>>(
        qkv_w, qkv_b, proj_w, tbl, ridx, mask, lepe_w, ws);
    qkv_gemm<<<dim3(5488), dim3(256), 0, stream>>>(x, ws);
    attn_head<<<dim3(12288), dim3(256), 0, stream>>>(lepe_b, ws);
    proj_gemm<<<dim3(2352), dim3(256), 0, stream>>>(proj_b, ws, out);
  } else {
    prep_fb<<<dim3(1101), dim3(256), 0, stream>>>(qkv_w, proj_w, tbl, ridx, ws);
    winattn_fb<<<dim3(2048), dim3(256), 0, stream>>>(x, mask, qkv_b, lepe_w, lepe_b,
                                                     proj_b, ws, out);
  }
}